// Round 1
// 221.433 us; speedup vs baseline: 1.0519x; 1.0519x over previous
//
#include <hip/hip_runtime.h>
#include <hip/hip_fp16.h>
#include <math.h>

#define N_NODES 50000
#define N_EDGES 800000
#define ET (N_EDGES + N_NODES)   // edges + self loops
#define IN_DIM 128
#define H1DIM 64                 // HEADS*HID
#define HEADS 8
#define HID 8
#define OUT_DIM 64
#define NEG_SLOPE 0.2f

#define SCAN_TILE 256
#define NTILES ((N_NODES + SCAN_TILE - 1) / SCAN_TILE)   // 196
#define RC 8                      // cached score iterations per lane (4 slots -> deg <= 32)
#define PF 6                      // prefetched feature-row iterations (deg <= 24)

#define LIN1_WAVES (N_NODES / 16)                // 3125 waves, 16 nodes each (MFMA tile)
#define LIN1_BLOCKS ((LIN1_WAVES + 3) / 4)       // 782
#define EB ((ET + 255) / 256)                    // 3321

typedef _Float16 half8 __attribute__((ext_vector_type(8)));
typedef float f32x4 __attribute__((ext_vector_type(4)));

__device__ __forceinline__ float lrelu(float v) { return v >= 0.f ? v : NEG_SLOPE * v; }

// real XCD id (gfx950; measured learn_hip m09). Wave-uniform.
__device__ __forceinline__ int xcc_id() {
    int v;
    asm volatile("s_getreg_b32 %0, hwreg(HW_REG_XCC_ID)" : "=s"(v));
    return v & 7;
}

// unpack 8 fp16 (raw uint4) and FMA into a[8]
__device__ __forceinline__ void fma8raw(uint4 u, float alpha, float* a) {
    float2 f0 = __half22float2(*(const __half2*)&u.x);
    float2 f1 = __half22float2(*(const __half2*)&u.y);
    float2 f2 = __half22float2(*(const __half2*)&u.z);
    float2 f3 = __half22float2(*(const __half2*)&u.w);
    a[0] += f0.x * alpha; a[1] += f0.y * alpha;
    a[2] += f1.x * alpha; a[3] += f1.y * alpha;
    a[4] += f2.x * alpha; a[5] += f2.y * alpha;
    a[6] += f3.x * alpha; a[7] += f3.y * alpha;
}

__device__ __forceinline__ void fma8h(const __half* __restrict__ base, float alpha, float* a) {
    fma8raw(*reinterpret_cast<const uint4*>(base), alpha, a);
}

// edge_index is int32 on device (validated round 4)
__device__ __forceinline__ void edge_nodes(const int* __restrict__ ei, int e, int& s, int& d) {
    if (e < N_EDGES) { s = ei[e]; d = ei[N_EDGES + e]; }
    else             { s = e - N_EDGES; d = s; }
}

// ---------------- fused: lin1 via split-fp16 MFMA (blocks [0,LIN1_BLOCKS)) +
//                  count-with-pos (rest) ----------------
// lin1: h = x_hi*W_hi + x_lo*W_hi + x_hi*W_lo  (fp32-equivalent accuracy).
// counters privatized by REAL XCD id -> copy c's cache lines only ever touched by XCD c.

__global__ __launch_bounds__(256) void cl1_kernel(
    const int* __restrict__ ei, int* __restrict__ cnt8, int* __restrict__ pos,
    const float* __restrict__ x, const float* __restrict__ W1,
    const float* __restrict__ a_src, const float* __restrict__ a_dst,
    __half* __restrict__ h1, float* __restrict__ ssrc, float* __restrict__ sdst)
{
    if (blockIdx.x >= LIN1_BLOCKS) {
        int i = (blockIdx.x - LIN1_BLOCKS) * 256 + threadIdx.x;
        if (i >= ET) return;
        int s, d; edge_nodes(ei, i, s, d);
        int c = xcc_id();
        int r = atomicAdd(&cnt8[c * N_NODES + d], 1);
        pos[i] = r | (c << 28);              // store copy id with the rank
        return;
    }

    // W1 -> fragment-ordered hi/lo LDS blobs. fragset f = ks*4+ct holds the
    // B operand for K-step ks (k in [ks*32, ks*32+32)) and col-tile ct
    // (c in [ct*16, ct*16+16)). Lane l, elem j: k = ks*32+(l>>4)*8+j,
    // c = ct*16+(l&15). One ds_read_b128 per fragment.
    __shared__ __half bH[16 * 512];   // 16 KiB
    __shared__ __half bL[16 * 512];   // 16 KiB

    int tid = threadIdx.x;
    #pragma unroll
    for (int i = 0; i < 32; ++i) {
        int idx = i * 256 + tid;
        int f = idx >> 9, rr = idx & 511;
        int l = rr >> 3, j = rr & 7;
        int ks = f >> 2, ct = f & 3;
        int k = ks * 32 + ((l >> 4) << 3) + j;
        int c = (ct << 4) + (l & 15);
        float w = W1[k * 64 + c];
        __half hi = __float2half(w);
        bH[idx] = hi;
        bL[idx] = __float2half(w - __half2float(hi));
    }
    __syncthreads();

    int wid = tid >> 6, t = tid & 63;
    int g = blockIdx.x * 4 + wid;
    if (g >= LIN1_WAVES) return;          // no barriers after this point
    int n0 = g * 16;
    int row = t & 15, kq = t >> 4;

    f32x4 acc[4] = {};
    const float* xp = x + (size_t)(n0 + row) * IN_DIM + kq * 8;
    #pragma unroll
    for (int ks = 0; ks < 4; ++ks) {
        float4 u0 = *reinterpret_cast<const float4*>(xp + ks * 32);
        float4 u1 = *reinterpret_cast<const float4*>(xp + ks * 32 + 4);
        float xv[8] = {u0.x, u0.y, u0.z, u0.w, u1.x, u1.y, u1.z, u1.w};
        half8 ah, al;
        #pragma unroll
        for (int j = 0; j < 8; ++j) {
            _Float16 h = (_Float16)xv[j];
            ah[j] = h;
            al[j] = (_Float16)(xv[j] - (float)h);
        }
        #pragma unroll
        for (int ct = 0; ct < 4; ++ct) {
            int f = ks * 4 + ct;
            half8 bh = *reinterpret_cast<const half8*>(&bH[f * 512 + t * 8]);
            half8 bl = *reinterpret_cast<const half8*>(&bL[f * 512 + t * 8]);
            acc[ct] = __builtin_amdgcn_mfma_f32_16x16x32_f16(ah, bh, acc[ct], 0, 0, 0);
            acc[ct] = __builtin_amdgcn_mfma_f32_16x16x32_f16(al, bh, acc[ct], 0, 0, 0);
            acc[ct] = __builtin_amdgcn_mfma_f32_16x16x32_f16(ah, bl, acc[ct], 0, 0, 0);
        }
    }

    // epilogue: D[row=(l>>4)*4+r][col=l&15] per col-tile ct.
    float asv[4], adv[4];
    #pragma unroll
    for (int ct = 0; ct < 4; ++ct) {
        asv[ct] = a_src[ct * 16 + (t & 15)];
        adv[ct] = a_dst[ct * 16 + (t & 15)];
    }
    int rbase = n0 + (t >> 4) * 4;
    #pragma unroll
    for (int r = 0; r < 4; ++r) {
        int n = rbase + r;
        #pragma unroll
        for (int ct = 0; ct < 4; ++ct) {
            float v = acc[ct][r];
            h1[(size_t)n * 64 + ct * 16 + (t & 15)] = __float2half(v);
            float ps = v * asv[ct], pd = v * adv[ct];
            ps += __shfl_xor(ps, 1); ps += __shfl_xor(ps, 2); ps += __shfl_xor(ps, 4);
            pd += __shfl_xor(pd, 1); pd += __shfl_xor(pd, 2); pd += __shfl_xor(pd, 4);
            if ((t & 7) == 0) {      // head hd = c>>3 = ct*2 + bit3(lane)
                int hd = ct * 2 + ((t >> 3) & 1);
                ssrc[n * 8 + hd] = ps;
                sdst[n * 8 + hd] = pd;
            }
        }
    }
}

// ---------------- scans ----------------

__global__ __launch_bounds__(SCAN_TILE) void scanA_kernel(
    const int* __restrict__ cnt8, int* __restrict__ row, int* __restrict__ aux)
{
    __shared__ int sh[SCAN_TILE];
    int t = threadIdx.x, i = blockIdx.x * SCAN_TILE + t;
    int v = 0;
    if (i < N_NODES) {
        #pragma unroll
        for (int c = 0; c < 8; ++c) v += cnt8[c * N_NODES + i];
    }
    sh[t] = v;
    __syncthreads();
    #pragma unroll
    for (int off = 1; off < SCAN_TILE; off <<= 1) {
        int add = (t >= off) ? sh[t - off] : 0;
        __syncthreads();
        sh[t] += add;
        __syncthreads();
    }
    if (i < N_NODES) row[i] = sh[t] - v;
    if (t == SCAN_TILE - 1) aux[blockIdx.x] = sh[t];
}

__global__ __launch_bounds__(SCAN_TILE) void scanB_kernel(int* __restrict__ aux, int* __restrict__ row) {
    __shared__ int sh[SCAN_TILE];
    int t = threadIdx.x;
    int v = (t < NTILES) ? aux[t] : 0;
    sh[t] = v;
    __syncthreads();
    #pragma unroll
    for (int off = 1; off < SCAN_TILE; off <<= 1) {
        int add = (t >= off) ? sh[t - off] : 0;
        __syncthreads();
        sh[t] += add;
        __syncthreads();
    }
    if (t < NTILES) aux[t] = sh[t] - v;
    if (t == NTILES - 1) row[N_NODES] = sh[t];
}

// finalize row and emit per-copy base offsets
__global__ __launch_bounds__(SCAN_TILE) void scanC_kernel(
    const int* __restrict__ aux, int* __restrict__ row,
    const int* __restrict__ cnt8, int* __restrict__ off8)
{
    int i = blockIdx.x * SCAN_TILE + threadIdx.x;
    if (i >= N_NODES) return;
    int r = row[i] + aux[i >> 8];
    row[i] = r;
    int run = r;
    #pragma unroll
    for (int c = 0; c < 8; ++c) {
        off8[c * N_NODES + i] = run;
        run += cnt8[c * N_NODES + i];
    }
}

// atomic-free fill: copy id recovered from pos high bits
__global__ void fill_kernel(const int* __restrict__ ei, const int* __restrict__ off8,
                            const int* __restrict__ pos, int* __restrict__ adj)
{
    int i = blockIdx.x * blockDim.x + threadIdx.x;
    if (i >= ET) return;
    int s, d; edge_nodes(ei, i, s, d);
    int pr = pos[i];
    int c = (unsigned)pr >> 28;
    int r = pr & 0x0FFFFFFF;
    adj[off8[c * N_NODES + d] + r] = s;
}

// ---------------- layer-1 node kernel: 2 nodes per wave ----------------
// lane t: half = t>>5 (node select), tt = t&31, slot = tt>>3 (4 slots), h = tt&7

__global__ __launch_bounds__(256) void l1_kernel(
    const int* __restrict__ row, const int* __restrict__ adj,
    const __half* __restrict__ h1, const float* __restrict__ s1, const float* __restrict__ t1,
    const float* __restrict__ b1, const float* __restrict__ W2,
    const float* __restrict__ as2, const float* __restrict__ ad2,
    __half* __restrict__ h2, float* __restrict__ s2, float* __restrict__ t2)
{
    int wid = threadIdx.x >> 6, t = threadIdx.x & 63;
    int half = t >> 5, tt = t & 31;
    int n = blockIdx.x * 8 + wid * 2 + half;
    int beg = row[n], end = row[n + 1];
    int slot = tt >> 3, h = tt & 7;
    float sd = t1[n * 8 + h];
    const int e0 = beg + slot;
    const int hb = half << 5;                     // half base lane

    // pass 1: gather scores + prefetch first PF feature rows
    int   sv[RC];
    float p[RC];
    uint4 raw[PF];
    float m = -3e38f;
    #pragma unroll
    for (int it = 0; it < RC; ++it) {
        int e = e0 + it * 4;
        bool ok = e < end;
        int s = ok ? adj[e] : n;
        sv[it] = s;
        float v = ok ? lrelu(s1[s * 8 + h] + sd) : -3e38f;
        p[it] = v;
        m = fmaxf(m, v);
        if (it < PF) raw[it] = *reinterpret_cast<const uint4*>(h1 + (size_t)s * 64 + h * 8);
    }
    for (int e = e0 + RC * 4; e < end; e += 4)    // improbable tail (deg > 32)
        m = fmaxf(m, lrelu(s1[adj[e] * 8 + h] + sd));
    m = fmaxf(m, __shfl_xor(m, 8));
    m = fmaxf(m, __shfl_xor(m, 16));

    float den = 0.f;
    #pragma unroll
    for (int it = 0; it < RC; ++it) {
        float pe = __expf(p[it] - m);             // empty slots -> 0
        p[it] = pe;
        den += pe;
    }
    for (int e = e0 + RC * 4; e < end; e += 4)
        den += __expf(lrelu(s1[adj[e] * 8 + h] + sd) - m);
    den += __shfl_xor(den, 8);
    den += __shfl_xor(den, 16);
    float inv = 1.f / (den + 1e-16f);

    // aggregate: lane accumulates channels h*8..h*8+7 of its node
    float a[8] = {0,0,0,0,0,0,0,0};
    #pragma unroll
    for (int it = 0; it < PF; ++it) fma8raw(raw[it], p[it] * inv, a);
    #pragma unroll
    for (int it = PF; it < RC; ++it) {
        int e = e0 + it * 4;
        if (e < end) fma8h(h1 + (size_t)sv[it] * 64 + h * 8, p[it] * inv, a);
    }
    for (int e = e0 + RC * 4; e < end; e += 4) {
        int s = adj[e];
        float alpha = __expf(lrelu(s1[s * 8 + h] + sd) - m) * inv;
        fma8h(h1 + (size_t)s * 64 + h * 8, alpha, a);
    }
    #pragma unroll
    for (int j = 0; j < 8; ++j) {
        a[j] += __shfl_xor(a[j], 8);
        a[j] += __shfl_xor(a[j], 16);
    }

    // redistribute: this lane needs ch0 = tt and ch1 = tt+32
    float ha0 = 0.f, ha1 = 0.f;
    int srcA = hb + (tt >> 3);
    #pragma unroll
    for (int j = 0; j < 8; ++j) {
        float vA = __shfl(a[j], srcA);
        float vB = __shfl(a[j], srcA + 4);
        if ((tt & 7) == j) { ha0 = vA; ha1 = vB; }
    }

    // bias + ELU
    ha0 += b1[tt];
    ha1 += b1[tt + 32];
    ha0 = ha0 > 0.f ? ha0 : (__expf(ha0) - 1.f);
    ha1 = ha1 > 0.f ? ha1 : (__expf(ha1) - 1.f);

    // fused lin2
    float c0 = 0.f, c1 = 0.f;
    #pragma unroll 8
    for (int k = 0; k < 32; ++k) {
        float w = __shfl(ha0, hb + k);
        c0 += w * W2[k * 64 + tt];
        c1 += w * W2[k * 64 + tt + 32];
    }
    #pragma unroll 8
    for (int k = 0; k < 32; ++k) {
        float w = __shfl(ha1, hb + k);
        c0 += w * W2[(k + 32) * 64 + tt];
        c1 += w * W2[(k + 32) * 64 + tt + 32];
    }
    h2[n * 64 + tt]      = __float2half(c0);
    h2[n * 64 + tt + 32] = __float2half(c1);

    // layer-2 scores (reduce within 32-lane half)
    float rs = c0 * as2[tt] + c1 * as2[tt + 32];
    float rd = c0 * ad2[tt] + c1 * ad2[tt + 32];
    #pragma unroll
    for (int mk = 16; mk >= 1; mk >>= 1) {
        rs += __shfl_xor(rs, mk);
        rd += __shfl_xor(rd, mk);
    }
    if (tt == 0) { s2[n] = rs; t2[n] = rd; }
}

// ---------------- layer-2 node kernel: 2 nodes per wave ----------------

__global__ __launch_bounds__(256) void l2_kernel(
    const int* __restrict__ row, const int* __restrict__ adj,
    const __half* __restrict__ h2, const float* __restrict__ s2, const float* __restrict__ t2,
    const float* __restrict__ b2, float* __restrict__ out)
{
    int wid = threadIdx.x >> 6, t = threadIdx.x & 63;
    int half = t >> 5, tt = t & 31;
    int n = blockIdx.x * 8 + wid * 2 + half;
    int beg = row[n], end = row[n + 1];
    int slot = tt >> 3, g = tt & 7;
    float sd = t2[n];
    const int e0 = beg + slot;

    int   sv[RC];
    float p[RC];
    uint4 raw[PF];
    float m = -3e38f;
    #pragma unroll
    for (int it = 0; it < RC; ++it) {
        int e = e0 + it * 4;
        bool ok = e < end;
        int s = ok ? adj[e] : n;
        sv[it] = s;
        float v = ok ? lrelu(s2[s] + sd) : -3e38f;
        p[it] = v;
        m = fmaxf(m, v);
        if (it < PF) raw[it] = *reinterpret_cast<const uint4*>(h2 + (size_t)s * 64 + g * 8);
    }
    for (int e = e0 + RC * 4; e < end; e += 4)
        m = fmaxf(m, lrelu(s2[adj[e]] + sd));
    m = fmaxf(m, __shfl_xor(m, 8));
    m = fmaxf(m, __shfl_xor(m, 16));

    float den = 0.f;
    #pragma unroll
    for (int it = 0; it < RC; ++it) {
        float pe = __expf(p[it] - m);
        p[it] = pe;
        den += pe;
    }
    for (int e = e0 + RC * 4; e < end; e += 4)
        den += __expf(lrelu(s2[adj[e]] + sd) - m);
    den += __shfl_xor(den, 8);
    den += __shfl_xor(den, 16);
    float inv = 1.f / (den + 1e-16f);

    float a[8] = {0,0,0,0,0,0,0,0};
    #pragma unroll
    for (int it = 0; it < PF; ++it) fma8raw(raw[it], p[it] * inv, a);
    #pragma unroll
    for (int it = PF; it < RC; ++it) {
        int e = e0 + it * 4;
        if (e < end) fma8h(h2 + (size_t)sv[it] * 64 + g * 8, p[it] * inv, a);
    }
    for (int e = e0 + RC * 4; e < end; e += 4) {
        int s = adj[e];
        float alpha = __expf(lrelu(s2[s] + sd) - m) * inv;
        fma8h(h2 + (size_t)s * 64 + g * 8, alpha, a);
    }
    #pragma unroll
    for (int j = 0; j < 8; ++j) {
        a[j] += __shfl_xor(a[j], 8);
        a[j] += __shfl_xor(a[j], 16);
    }
    if (slot == 0) {
        float4 o0 = make_float4(a[0] + b2[g * 8 + 0], a[1] + b2[g * 8 + 1],
                                a[2] + b2[g * 8 + 2], a[3] + b2[g * 8 + 3]);
        float4 o1 = make_float4(a[4] + b2[g * 8 + 4], a[5] + b2[g * 8 + 5],
                                a[6] + b2[g * 8 + 6], a[7] + b2[g * 8 + 7]);
        float4* op = (float4*)(out + (size_t)n * 64 + g * 8);
        op[0] = o0; op[1] = o1;
    }
}

extern "C" void kernel_launch(void* const* d_in, const int* in_sizes, int n_in,
                              void* d_out, int out_size, void* d_ws, size_t ws_size,
                              hipStream_t stream)
{
    const float* x   = (const float*)d_in[0];
    const int* ei    = (const int*)d_in[1];
    const float* W1  = (const float*)d_in[2];
    const float* as1 = (const float*)d_in[3];
    const float* ad1 = (const float*)d_in[4];
    const float* b1  = (const float*)d_in[5];
    const float* W2  = (const float*)d_in[6];
    const float* as2 = (const float*)d_in[7];
    const float* ad2 = (const float*)d_in[8];
    const float* b2  = (const float*)d_in[9];
    float* out = (float*)d_out;

    char* wsb = (char*)d_ws;
    __half* h1  = (__half*)wsb;                       // N*64 fp16
    __half* h2  = h1 + (size_t)N_NODES * 64;          // N*64 fp16
    float*  s1  = (float*)(h2 + (size_t)N_NODES * 64);// N*8
    float*  t1  = s1 + N_NODES * 8;                   // N*8
    float*  s2  = t1 + N_NODES * 8;                   // N
    float*  t2  = s2 + N_NODES;                       // N
    int*    cnt8 = (int*)(t2 + N_NODES);              // 8*N
    int*    off8 = cnt8 + 8 * N_NODES;                // 8*N
    int*    rowp = off8 + 8 * N_NODES;                // N+1
    int*    aux  = rowp + N_NODES + 1;                // NTILES
    int*    adj  = aux + NTILES;                      // ET
    int*    pos  = adj + ET;                          // ET

    hipMemsetAsync(cnt8, 0, 8 * N_NODES * sizeof(int), stream);

    cl1_kernel<<<LIN1_BLOCKS + EB, 256, 0, stream>>>(ei, cnt8, pos, x, W1, as1, ad1, h1, s1, t1);

    scanA_kernel<<<NTILES, SCAN_TILE, 0, stream>>>(cnt8, rowp, aux);
    scanB_kernel<<<1, SCAN_TILE, 0, stream>>>(aux, rowp);
    scanC_kernel<<<NTILES, SCAN_TILE, 0, stream>>>(aux, rowp, cnt8, off8);
    fill_kernel<<<EB, 256, 0, stream>>>(ei, off8, pos, adj);

    l1_kernel<<<N_NODES / 8, 256, 0, stream>>>(rowp, adj, h1, s1, t1,
                                               b1, W2, as2, ad2, h2, s2, t2);

    l2_kernel<<<N_NODES / 8, 256, 0, stream>>>(rowp, adj, h2, s2, t2, b2, out);
}

// Round 2
// 215.178 us; speedup vs baseline: 1.0825x; 1.0291x over previous
//
#include <hip/hip_runtime.h>
#include <hip/hip_fp16.h>
#include <math.h>
#include <stdint.h>

#define N_NODES 50000
#define N_EDGES 800000
#define ET (N_EDGES + N_NODES)   // edges + self loops
#define IN_DIM 128
#define H1DIM 64                 // HEADS*HID
#define HEADS 8
#define HID 8
#define OUT_DIM 64
#define NEG_SLOPE 0.2f

#define SCAN_TILE 256
#define NTILES ((N_NODES + SCAN_TILE - 1) / SCAN_TILE)   // 196
#define RC 8                      // cached score iterations per lane (4 slots -> deg <= 32)
#define PF 6                      // prefetched feature-row iterations (deg <= 24)

#define LIN1_WAVES (N_NODES / 16)                // 3125 waves, 16 nodes each (MFMA tile)
#define LIN1_BLOCKS ((LIN1_WAVES + 3) / 4)       // 782
#define LIN2_WAVES (N_NODES / 16)                // 3125
#define LIN2_BLOCKS ((LIN2_WAVES + 3) / 4)       // 782
#define EB ((ET + 255) / 256)                    // 3321

typedef _Float16 half8 __attribute__((ext_vector_type(8)));
typedef float f32x4 __attribute__((ext_vector_type(4)));

__device__ __forceinline__ float lrelu(float v) { return v >= 0.f ? v : NEG_SLOPE * v; }

// real XCD id (gfx950; measured learn_hip m09). Wave-uniform.
__device__ __forceinline__ int xcc_id() {
    int v;
    asm volatile("s_getreg_b32 %0, hwreg(HW_REG_XCC_ID)" : "=s"(v));
    return v & 7;
}

// unpack 8 fp16 (raw uint4) and FMA into a[8]
__device__ __forceinline__ void fma8raw(uint4 u, float alpha, float* a) {
    float2 f0 = __half22float2(*(const __half2*)&u.x);
    float2 f1 = __half22float2(*(const __half2*)&u.y);
    float2 f2 = __half22float2(*(const __half2*)&u.z);
    float2 f3 = __half22float2(*(const __half2*)&u.w);
    a[0] += f0.x * alpha; a[1] += f0.y * alpha;
    a[2] += f1.x * alpha; a[3] += f1.y * alpha;
    a[4] += f2.x * alpha; a[5] += f2.y * alpha;
    a[6] += f3.x * alpha; a[7] += f3.y * alpha;
}

__device__ __forceinline__ void fma8h(const __half* __restrict__ base, float alpha, float* a) {
    fma8raw(*reinterpret_cast<const uint4*>(base), alpha, a);
}

// edge_index is int32 on device (validated round 4)
__device__ __forceinline__ void edge_nodes(const int* __restrict__ ei, int e, int& s, int& d) {
    if (e < N_EDGES) { s = ei[e]; d = ei[N_EDGES + e]; }
    else             { s = e - N_EDGES; d = s; }
}

// ---------------- fused: lin1 via split-fp16 MFMA (blocks [0,LIN1_BLOCKS)) +
//                  count-with-pos (rest) ----------------
// lin1: h = x_hi*W_hi + x_lo*W_hi + x_hi*W_lo  (fp32-equivalent accuracy).
// counters privatized by REAL XCD id -> copy c's cache lines only ever touched by XCD c.

__global__ __launch_bounds__(256) void cl1_kernel(
    const int* __restrict__ ei, int* __restrict__ cnt8, int* __restrict__ pos,
    const float* __restrict__ x, const float* __restrict__ W1,
    const float* __restrict__ a_src, const float* __restrict__ a_dst,
    __half* __restrict__ h1, float* __restrict__ ssrc, float* __restrict__ sdst)
{
    if (blockIdx.x >= LIN1_BLOCKS) {
        int i = (blockIdx.x - LIN1_BLOCKS) * 256 + threadIdx.x;
        if (i >= ET) return;
        int s, d; edge_nodes(ei, i, s, d);
        int c = xcc_id();
        int r = atomicAdd(&cnt8[c * N_NODES + d], 1);
        pos[i] = r | (c << 28);              // store copy id with the rank
        return;
    }

    // W1 -> fragment-ordered hi/lo LDS blobs. fragset f = ks*4+ct holds the
    // B operand for K-step ks (k in [ks*32, ks*32+32)) and col-tile ct
    // (c in [ct*16, ct*16+16)). Lane l, elem j: k = ks*32+(l>>4)*8+j,
    // c = ct*16+(l&15). One ds_read_b128 per fragment.
    __shared__ __half bH[16 * 512];   // 16 KiB
    __shared__ __half bL[16 * 512];   // 16 KiB

    int tid = threadIdx.x;
    #pragma unroll
    for (int i = 0; i < 32; ++i) {
        int idx = i * 256 + tid;
        int f = idx >> 9, rr = idx & 511;
        int l = rr >> 3, j = rr & 7;
        int ks = f >> 2, ct = f & 3;
        int k = ks * 32 + ((l >> 4) << 3) + j;
        int c = (ct << 4) + (l & 15);
        float w = W1[k * 64 + c];
        __half hi = __float2half(w);
        bH[idx] = hi;
        bL[idx] = __float2half(w - __half2float(hi));
    }
    __syncthreads();

    int wid = tid >> 6, t = tid & 63;
    int g = blockIdx.x * 4 + wid;
    if (g >= LIN1_WAVES) return;          // no barriers after this point
    int n0 = g * 16;
    int row = t & 15, kq = t >> 4;

    f32x4 acc[4] = {};
    const float* xp = x + (size_t)(n0 + row) * IN_DIM + kq * 8;
    #pragma unroll
    for (int ks = 0; ks < 4; ++ks) {
        float4 u0 = *reinterpret_cast<const float4*>(xp + ks * 32);
        float4 u1 = *reinterpret_cast<const float4*>(xp + ks * 32 + 4);
        float xv[8] = {u0.x, u0.y, u0.z, u0.w, u1.x, u1.y, u1.z, u1.w};
        half8 ah, al;
        #pragma unroll
        for (int j = 0; j < 8; ++j) {
            _Float16 h = (_Float16)xv[j];
            ah[j] = h;
            al[j] = (_Float16)(xv[j] - (float)h);
        }
        #pragma unroll
        for (int ct = 0; ct < 4; ++ct) {
            int f = ks * 4 + ct;
            half8 bh = *reinterpret_cast<const half8*>(&bH[f * 512 + t * 8]);
            half8 bl = *reinterpret_cast<const half8*>(&bL[f * 512 + t * 8]);
            acc[ct] = __builtin_amdgcn_mfma_f32_16x16x32_f16(ah, bh, acc[ct], 0, 0, 0);
            acc[ct] = __builtin_amdgcn_mfma_f32_16x16x32_f16(al, bh, acc[ct], 0, 0, 0);
            acc[ct] = __builtin_amdgcn_mfma_f32_16x16x32_f16(ah, bl, acc[ct], 0, 0, 0);
        }
    }

    // epilogue: D[row=(l>>4)*4+r][col=l&15] per col-tile ct.
    float asv[4], adv[4];
    #pragma unroll
    for (int ct = 0; ct < 4; ++ct) {
        asv[ct] = a_src[ct * 16 + (t & 15)];
        adv[ct] = a_dst[ct * 16 + (t & 15)];
    }
    int rbase = n0 + (t >> 4) * 4;
    #pragma unroll
    for (int r = 0; r < 4; ++r) {
        int n = rbase + r;
        #pragma unroll
        for (int ct = 0; ct < 4; ++ct) {
            float v = acc[ct][r];
            h1[(size_t)n * 64 + ct * 16 + (t & 15)] = __float2half(v);
            float ps = v * asv[ct], pd = v * adv[ct];
            ps += __shfl_xor(ps, 1); ps += __shfl_xor(ps, 2); ps += __shfl_xor(ps, 4);
            pd += __shfl_xor(pd, 1); pd += __shfl_xor(pd, 2); pd += __shfl_xor(pd, 4);
            if ((t & 7) == 0) {      // head hd = c>>3 = ct*2 + bit3(lane)
                int hd = ct * 2 + ((t >> 3) & 1);
                ssrc[n * 8 + hd] = ps;
                sdst[n * 8 + hd] = pd;
            }
        }
    }
}

// ---------------- scans ----------------

__global__ __launch_bounds__(SCAN_TILE) void scanA_kernel(
    const int* __restrict__ cnt8, int* __restrict__ row, int* __restrict__ aux)
{
    __shared__ int sh[SCAN_TILE];
    int t = threadIdx.x, i = blockIdx.x * SCAN_TILE + t;
    int v = 0;
    if (i < N_NODES) {
        #pragma unroll
        for (int c = 0; c < 8; ++c) v += cnt8[c * N_NODES + i];
    }
    sh[t] = v;
    __syncthreads();
    #pragma unroll
    for (int off = 1; off < SCAN_TILE; off <<= 1) {
        int add = (t >= off) ? sh[t - off] : 0;
        __syncthreads();
        sh[t] += add;
        __syncthreads();
    }
    if (i < N_NODES) row[i] = sh[t] - v;
    if (t == SCAN_TILE - 1) aux[blockIdx.x] = sh[t];
}

__global__ __launch_bounds__(SCAN_TILE) void scanB_kernel(int* __restrict__ aux, int* __restrict__ row) {
    __shared__ int sh[SCAN_TILE];
    int t = threadIdx.x;
    int v = (t < NTILES) ? aux[t] : 0;
    sh[t] = v;
    __syncthreads();
    #pragma unroll
    for (int off = 1; off < SCAN_TILE; off <<= 1) {
        int add = (t >= off) ? sh[t - off] : 0;
        __syncthreads();
        sh[t] += add;
        __syncthreads();
    }
    if (t < NTILES) aux[t] = sh[t] - v;
    if (t == NTILES - 1) row[N_NODES] = sh[t];
}

// finalize row and emit per-copy base offsets
__global__ __launch_bounds__(SCAN_TILE) void scanC_kernel(
    const int* __restrict__ aux, int* __restrict__ row,
    const int* __restrict__ cnt8, int* __restrict__ off8)
{
    int i = blockIdx.x * SCAN_TILE + threadIdx.x;
    if (i >= N_NODES) return;
    int r = row[i] + aux[i >> 8];
    row[i] = r;
    int run = r;
    #pragma unroll
    for (int c = 0; c < 8; ++c) {
        off8[c * N_NODES + i] = run;
        run += cnt8[c * N_NODES + i];
    }
}

// atomic-free fill: copy id recovered from pos high bits
__global__ void fill_kernel(const int* __restrict__ ei, const int* __restrict__ off8,
                            const int* __restrict__ pos, int* __restrict__ adj)
{
    int i = blockIdx.x * blockDim.x + threadIdx.x;
    if (i >= ET) return;
    int s, d; edge_nodes(ei, i, s, d);
    int pr = pos[i];
    int c = (unsigned)pr >> 28;
    int r = pr & 0x0FFFFFFF;
    adj[off8[c * N_NODES + d] + r] = s;
}

// ---------------- layer-1 node kernel: 2 nodes per wave ----------------
// lane t: half = t>>5 (node select), tt = t&31, slot = tt>>3 (4 slots), h = tt&7
// ends at bias+ELU; writes ha (fp32). lin2 moved to MFMA kernel.

__global__ __launch_bounds__(256) void l1_kernel(
    const int* __restrict__ row, const int* __restrict__ adj,
    const __half* __restrict__ h1, const float* __restrict__ s1, const float* __restrict__ t1,
    const float* __restrict__ b1, float* __restrict__ ha)
{
    int wid = threadIdx.x >> 6, t = threadIdx.x & 63;
    int half = t >> 5, tt = t & 31;
    int n = blockIdx.x * 8 + wid * 2 + half;
    int beg = row[n], end = row[n + 1];
    int slot = tt >> 3, h = tt & 7;
    float sd = t1[n * 8 + h];
    const int e0 = beg + slot;

    // pass 1: gather scores + prefetch first PF feature rows
    int   sv[RC];
    float p[RC];
    uint4 raw[PF];
    float m = -3e38f;
    #pragma unroll
    for (int it = 0; it < RC; ++it) {
        int e = e0 + it * 4;
        bool ok = e < end;
        int s = ok ? adj[e] : n;
        sv[it] = s;
        float v = ok ? lrelu(s1[s * 8 + h] + sd) : -3e38f;
        p[it] = v;
        m = fmaxf(m, v);
        if (it < PF) raw[it] = *reinterpret_cast<const uint4*>(h1 + (size_t)s * 64 + h * 8);
    }
    for (int e = e0 + RC * 4; e < end; e += 4)    // improbable tail (deg > 32)
        m = fmaxf(m, lrelu(s1[adj[e] * 8 + h] + sd));
    m = fmaxf(m, __shfl_xor(m, 8));
    m = fmaxf(m, __shfl_xor(m, 16));

    float den = 0.f;
    #pragma unroll
    for (int it = 0; it < RC; ++it) {
        float pe = __expf(p[it] - m);             // empty slots -> 0
        p[it] = pe;
        den += pe;
    }
    for (int e = e0 + RC * 4; e < end; e += 4)
        den += __expf(lrelu(s1[adj[e] * 8 + h] + sd) - m);
    den += __shfl_xor(den, 8);
    den += __shfl_xor(den, 16);
    float inv = 1.f / (den + 1e-16f);

    // aggregate: lane accumulates channels h*8..h*8+7 of its node
    float a[8] = {0,0,0,0,0,0,0,0};
    #pragma unroll
    for (int it = 0; it < PF; ++it) fma8raw(raw[it], p[it] * inv, a);
    #pragma unroll
    for (int it = PF; it < RC; ++it) {
        int e = e0 + it * 4;
        if (e < end) fma8h(h1 + (size_t)sv[it] * 64 + h * 8, p[it] * inv, a);
    }
    for (int e = e0 + RC * 4; e < end; e += 4) {
        int s = adj[e];
        float alpha = __expf(lrelu(s1[s * 8 + h] + sd) - m) * inv;
        fma8h(h1 + (size_t)s * 64 + h * 8, alpha, a);
    }
    #pragma unroll
    for (int j = 0; j < 8; ++j) {
        a[j] += __shfl_xor(a[j], 8);
        a[j] += __shfl_xor(a[j], 16);
    }

    // bias + ELU; each slot writes 2 channels (c = h*8 + slot*2 + {0,1})
    int j0 = slot * 2;
    float v0 = a[j0]     + b1[h * 8 + j0];
    float v1 = a[j0 + 1] + b1[h * 8 + j0 + 1];
    v0 = v0 > 0.f ? v0 : (__expf(v0) - 1.f);
    v1 = v1 > 0.f ? v1 : (__expf(v1) - 1.f);
    *reinterpret_cast<float2*>(ha + (size_t)n * 64 + h * 8 + j0) = make_float2(v0, v1);
}

// ---------------- lin2 via split-fp16 MFMA: h2 = ha @ W2, + layer-2 scores ----
// same fragment scheme as cl1; K=64 (2 K-steps), 16 nodes per wave.

__global__ __launch_bounds__(256) void lin2_kernel(
    const float* __restrict__ ha, const float* __restrict__ W2,
    const float* __restrict__ as2, const float* __restrict__ ad2,
    __half* __restrict__ h2, float* __restrict__ s2, float* __restrict__ t2)
{
    __shared__ __half bH[8 * 512];   // 8 KiB
    __shared__ __half bL[8 * 512];   // 8 KiB

    int tid = threadIdx.x;
    #pragma unroll
    for (int i = 0; i < 16; ++i) {
        int idx = i * 256 + tid;                 // 4096 elements
        int f = idx >> 9, rr = idx & 511;
        int l = rr >> 3, j = rr & 7;
        int ks = f >> 2, ct = f & 3;
        int k = ks * 32 + ((l >> 4) << 3) + j;
        int c = (ct << 4) + (l & 15);
        float w = W2[k * 64 + c];
        __half hi = __float2half(w);
        bH[idx] = hi;
        bL[idx] = __float2half(w - __half2float(hi));
    }
    __syncthreads();

    int wid = tid >> 6, t = tid & 63;
    int g = blockIdx.x * 4 + wid;
    if (g >= LIN2_WAVES) return;
    int n0 = g * 16;
    int row = t & 15, kq = t >> 4;

    f32x4 acc[4] = {};
    const float* xp = ha + (size_t)(n0 + row) * 64 + kq * 8;
    #pragma unroll
    for (int ks = 0; ks < 2; ++ks) {
        float4 u0 = *reinterpret_cast<const float4*>(xp + ks * 32);
        float4 u1 = *reinterpret_cast<const float4*>(xp + ks * 32 + 4);
        float xv[8] = {u0.x, u0.y, u0.z, u0.w, u1.x, u1.y, u1.z, u1.w};
        half8 ah, al;
        #pragma unroll
        for (int j = 0; j < 8; ++j) {
            _Float16 hh = (_Float16)xv[j];
            ah[j] = hh;
            al[j] = (_Float16)(xv[j] - (float)hh);
        }
        #pragma unroll
        for (int ct = 0; ct < 4; ++ct) {
            int f = ks * 4 + ct;
            half8 bh = *reinterpret_cast<const half8*>(&bH[f * 512 + t * 8]);
            half8 bl = *reinterpret_cast<const half8*>(&bL[f * 512 + t * 8]);
            acc[ct] = __builtin_amdgcn_mfma_f32_16x16x32_f16(ah, bh, acc[ct], 0, 0, 0);
            acc[ct] = __builtin_amdgcn_mfma_f32_16x16x32_f16(al, bh, acc[ct], 0, 0, 0);
            acc[ct] = __builtin_amdgcn_mfma_f32_16x16x32_f16(ah, bl, acc[ct], 0, 0, 0);
        }
    }

    // epilogue: h2 fp16 store + full-row score reductions (over all 64 cols)
    float asv[4], adv[4];
    #pragma unroll
    for (int ct = 0; ct < 4; ++ct) {
        asv[ct] = as2[ct * 16 + (t & 15)];
        adv[ct] = ad2[ct * 16 + (t & 15)];
    }
    int rbase = n0 + (t >> 4) * 4;
    #pragma unroll
    for (int r = 0; r < 4; ++r) {
        int n = rbase + r;
        float ps = 0.f, pd = 0.f;
        #pragma unroll
        for (int ct = 0; ct < 4; ++ct) {
            float v = acc[ct][r];
            h2[(size_t)n * 64 + ct * 16 + (t & 15)] = __float2half(v);
            ps += v * asv[ct];
            pd += v * adv[ct];
        }
        ps += __shfl_xor(ps, 1); ps += __shfl_xor(ps, 2);
        ps += __shfl_xor(ps, 4); ps += __shfl_xor(ps, 8);
        pd += __shfl_xor(pd, 1); pd += __shfl_xor(pd, 2);
        pd += __shfl_xor(pd, 4); pd += __shfl_xor(pd, 8);
        if ((t & 15) == 0) { s2[n] = ps; t2[n] = pd; }
    }
}

// ---------------- layer-2 node kernel: 2 nodes per wave ----------------

__global__ __launch_bounds__(256) void l2_kernel(
    const int* __restrict__ row, const int* __restrict__ adj,
    const __half* __restrict__ h2, const float* __restrict__ s2, const float* __restrict__ t2,
    const float* __restrict__ b2, float* __restrict__ out)
{
    int wid = threadIdx.x >> 6, t = threadIdx.x & 63;
    int half = t >> 5, tt = t & 31;
    int n = blockIdx.x * 8 + wid * 2 + half;
    int beg = row[n], end = row[n + 1];
    int slot = tt >> 3, g = tt & 7;
    float sd = t2[n];
    const int e0 = beg + slot;

    int   sv[RC];
    float p[RC];
    uint4 raw[PF];
    float m = -3e38f;
    #pragma unroll
    for (int it = 0; it < RC; ++it) {
        int e = e0 + it * 4;
        bool ok = e < end;
        int s = ok ? adj[e] : n;
        sv[it] = s;
        float v = ok ? lrelu(s2[s] + sd) : -3e38f;
        p[it] = v;
        m = fmaxf(m, v);
        if (it < PF) raw[it] = *reinterpret_cast<const uint4*>(h2 + (size_t)s * 64 + g * 8);
    }
    for (int e = e0 + RC * 4; e < end; e += 4)
        m = fmaxf(m, lrelu(s2[adj[e]] + sd));
    m = fmaxf(m, __shfl_xor(m, 8));
    m = fmaxf(m, __shfl_xor(m, 16));

    float den = 0.f;
    #pragma unroll
    for (int it = 0; it < RC; ++it) {
        float pe = __expf(p[it] - m);
        p[it] = pe;
        den += pe;
    }
    for (int e = e0 + RC * 4; e < end; e += 4)
        den += __expf(lrelu(s2[adj[e]] + sd) - m);
    den += __shfl_xor(den, 8);
    den += __shfl_xor(den, 16);
    float inv = 1.f / (den + 1e-16f);

    float a[8] = {0,0,0,0,0,0,0,0};
    #pragma unroll
    for (int it = 0; it < PF; ++it) fma8raw(raw[it], p[it] * inv, a);
    #pragma unroll
    for (int it = PF; it < RC; ++it) {
        int e = e0 + it * 4;
        if (e < end) fma8h(h2 + (size_t)sv[it] * 64 + g * 8, p[it] * inv, a);
    }
    for (int e = e0 + RC * 4; e < end; e += 4) {
        int s = adj[e];
        float alpha = __expf(lrelu(s2[s] + sd) - m) * inv;
        fma8h(h2 + (size_t)s * 64 + g * 8, alpha, a);
    }
    #pragma unroll
    for (int j = 0; j < 8; ++j) {
        a[j] += __shfl_xor(a[j], 8);
        a[j] += __shfl_xor(a[j], 16);
    }
    if (slot == 0) {
        float4 o0 = make_float4(a[0] + b2[g * 8 + 0], a[1] + b2[g * 8 + 1],
                                a[2] + b2[g * 8 + 2], a[3] + b2[g * 8 + 3]);
        float4 o1 = make_float4(a[4] + b2[g * 8 + 4], a[5] + b2[g * 8 + 5],
                                a[6] + b2[g * 8 + 6], a[7] + b2[g * 8 + 7]);
        float4* op = (float4*)(out + (size_t)n * 64 + g * 8);
        op[0] = o0; op[1] = o1;
    }
}

extern "C" void kernel_launch(void* const* d_in, const int* in_sizes, int n_in,
                              void* d_out, int out_size, void* d_ws, size_t ws_size,
                              hipStream_t stream)
{
    const float* x   = (const float*)d_in[0];
    const int* ei    = (const int*)d_in[1];
    const float* W1  = (const float*)d_in[2];
    const float* as1 = (const float*)d_in[3];
    const float* ad1 = (const float*)d_in[4];
    const float* b1  = (const float*)d_in[5];
    const float* W2  = (const float*)d_in[6];
    const float* as2 = (const float*)d_in[7];
    const float* ad2 = (const float*)d_in[8];
    const float* b2  = (const float*)d_in[9];
    float* out = (float*)d_out;

    char* wsb = (char*)d_ws;
    __half* h1  = (__half*)wsb;                       // N*64 fp16
    __half* h2  = h1 + (size_t)N_NODES * 64;          // N*64 fp16
    float*  s1  = (float*)(h2 + (size_t)N_NODES * 64);// N*8
    float*  t1  = s1 + N_NODES * 8;                   // N*8
    float*  s2  = t1 + N_NODES * 8;                   // N
    float*  t2  = s2 + N_NODES;                       // N
    int*    cnt8 = (int*)(t2 + N_NODES);              // 8*N
    int*    off8 = cnt8 + 8 * N_NODES;                // 8*N
    int*    rowp = off8 + 8 * N_NODES;                // N+1
    int*    aux  = rowp + N_NODES + 1;                // NTILES
    int*    adj  = aux + NTILES;                      // ET
    int*    pos  = adj + ET;                          // ET
    float*  ha   = (float*)(((uintptr_t)(pos + ET) + 15) & ~(uintptr_t)15); // N*64 fp32

    hipMemsetAsync(cnt8, 0, 8 * N_NODES * sizeof(int), stream);

    cl1_kernel<<<LIN1_BLOCKS + EB, 256, 0, stream>>>(ei, cnt8, pos, x, W1, as1, ad1, h1, s1, t1);

    scanA_kernel<<<NTILES, SCAN_TILE, 0, stream>>>(cnt8, rowp, aux);
    scanB_kernel<<<1, SCAN_TILE, 0, stream>>>(aux, rowp);
    scanC_kernel<<<NTILES, SCAN_TILE, 0, stream>>>(aux, rowp, cnt8, off8);
    fill_kernel<<<EB, 256, 0, stream>>>(ei, off8, pos, adj);

    l1_kernel<<<N_NODES / 8, 256, 0, stream>>>(rowp, adj, h1, s1, t1, b1, ha);

    lin2_kernel<<<LIN2_BLOCKS, 256, 0, stream>>>(ha, W2, as2, ad2, h2, s2, t2);

    l2_kernel<<<N_NODES / 8, 256, 0, stream>>>(rowp, adj, h2, s2, t2, b2, out);
}